// Round 2
// baseline (653.629 us; speedup 1.0000x reference)
//
#include <hip/hip_runtime.h>
#include <stdint.h>

// BitInput: reproduce jax.random.uniform(key(42), [1024,512,256]) bit-exactly,
// assuming modern JAX default jax_threefry_partitionable=True:
//   counts = iota(uint64, 2^27)
//   (o0,o1) = threefry2x32((0,42), (hi32(count)=0, lo32(count)=i))
//   bits[i] = o0 ^ o1
//   u = bitcast((bits>>9)|0x3f800000) - 1.0f        in [0,1)
//   out[i] = (u < p[i>>8]) ? 1.0f : 0.0f
// (Round-1 kernel implemented the LEGACY split-iota path; failed absmax=1.0.)

__device__ __forceinline__ uint32_t rotl32(uint32_t x, uint32_t r) {
    return (x << r) | (x >> (32u - r));   // v_alignbit_b32
}

__device__ __forceinline__ void threefry2x32_0_42(uint32_t x0, uint32_t x1,
                                                  uint32_t& o0, uint32_t& o1) {
    const uint32_t k0 = 0u;
    const uint32_t k1 = 42u;
    const uint32_t k2 = 0x1BD11BDAu ^ k0 ^ k1;   // 0x1BD11BF0
    x0 += k0; x1 += k1;
#define TF_RND(r) { x0 += x1; x1 = rotl32(x1, (r)); x1 ^= x0; }
    TF_RND(13u) TF_RND(15u) TF_RND(26u) TF_RND(6u)
    x0 += k1; x1 += k2 + 1u;
    TF_RND(17u) TF_RND(29u) TF_RND(16u) TF_RND(24u)
    x0 += k2; x1 += k0 + 2u;
    TF_RND(13u) TF_RND(15u) TF_RND(26u) TF_RND(6u)
    x0 += k0; x1 += k1 + 3u;
    TF_RND(17u) TF_RND(29u) TF_RND(16u) TF_RND(24u)
    x0 += k1; x1 += k2 + 4u;
    TF_RND(13u) TF_RND(15u) TF_RND(26u) TF_RND(6u)
    x0 += k2; x1 += k0 + 5u;
#undef TF_RND
    o0 = x0; o1 = x1;
}

__global__ __launch_bounds__(256) void bitinput_kernel(
        const float* __restrict__ inp, float* __restrict__ out, uint32_t n) {
    uint32_t t  = blockIdx.x * blockDim.x + threadIdx.x;
    uint32_t i0 = t * 4u;                 // 4 consecutive flat outputs/thread
    if (i0 >= n) return;

    // 4 | 256 and i0 % 4 == 0, so all 4 outputs share one probability.
    // Input is 2 MiB -> L2-resident; each p is read by 64 consecutive threads.
    float p = inp[i0 >> 8];

    float4 r;
    float* rp = reinterpret_cast<float*>(&r);

#pragma unroll
    for (int k = 0; k < 4; ++k) {
        uint32_t o0, o1;
        // counter = (uint64)(i0+k): hi32 = 0, lo32 = i0+k
        threefry2x32_0_42(0u, i0 + (uint32_t)k, o0, o1);
        uint32_t bits = o0 ^ o1;          // partitionable 32-bit output
        float u = __uint_as_float((bits >> 9) | 0x3f800000u) - 1.0f;
        rp[k] = (u < p) ? 1.0f : 0.0f;
    }

    // coalesced 16 B/lane store
    reinterpret_cast<float4*>(out)[t] = r;
}

extern "C" void kernel_launch(void* const* d_in, const int* in_sizes, int n_in,
                              void* d_out, int out_size, void* d_ws, size_t ws_size,
                              hipStream_t stream) {
    const float* inp = (const float*)d_in[0];
    float* out = (float*)d_out;

    uint32_t n = (uint32_t)out_size;            // 1024*512*256 = 2^27
    uint32_t threads_needed = n >> 2;           // 4 outputs per thread
    dim3 block(256);
    dim3 grid((threads_needed + block.x - 1) / block.x);
    bitinput_kernel<<<grid, block, 0, stream>>>(inp, out, n);
}